// Round 15
// baseline (42.373 us; speedup 1.0000x reference)
//
#include <hip/hip_runtime.h>
#include <math.h>

#define F_IN  128
#define F_OUT 256
#define GBITS 5            // 32 nodes per group
#define G_MAX 380          // max groups (G = ceil(n/32) = 375 for n=12000)
#define WPR   376          // padded words per LDS bitmap row (>= ceil(n/32))
#define SBLK  128          // scatter blocks
#define STHR  512          // scatter threads per block
#define CSLOT 32           // slots per (group, block) cell; fill ~ Poisson(16)

// ---------------------------------------------------------------------------
// S: single-pass cell scatter. No global atomics, no pre-zeroed memory.
// Each block streams its edge chunk ONCE; slot = LDS cur[g]++ places the item
// in bucket[g][b][slot] ([group][block][slot] layout -> dedup reads each
// group as ONE contiguous 16 KB run). Items past CSLOT go to this block's
// private overflow (capacity = whole chunk: can never drop). Counts are
// WRITTEN at the end (cnt_t, ovfcnt) -> no memset node anywhere.
// Cell/ovf SPLIT is race-dependent but the per-group item SET is exact;
// downstream consumes via idempotent OR => bitwise-deterministic output.
// pack(cell) = (node&31)<<16 | other ; pack(ovf) = node<<16 | other.
// ---------------------------------------------------------------------------
__global__ __launch_bounds__(STHR)
void k_scatter_cells(const int* __restrict__ ei, int E, int G,
                     int* __restrict__ cnt_t,       // [G][SBLK]  (written)
                     int* __restrict__ ovfcnt,      // [SBLK]     (written)
                     unsigned* __restrict__ bucket, // [G][SBLK][CSLOT]
                     unsigned* __restrict__ ovf,    // [SBLK][ovfcap]
                     int ovfcap) {
    __shared__ int cur[G_MAX];
    __shared__ int ocur;
    int b = blockIdx.x, t = threadIdx.x;
    for (int g = t; g < G; g += STHR) cur[g] = 0;
    if (t == 0) ocur = 0;
    __syncthreads();

    int C = (E + (int)gridDim.x - 1) / (int)gridDim.x;
    int e0 = b * C, e1 = min(E, e0 + C);
    unsigned* myovf = ovf + (size_t)b * ovfcap;
    for (int e = e0 + t; e < e1; e += STHR) {
        int a = ei[e], c = ei[E + e];
        int ga = a >> GBITS, gc = c >> GBITS;
        int s1 = atomicAdd(&cur[ga], 1);
        if (s1 < CSLOT)
            bucket[((size_t)ga * SBLK + b) * CSLOT + s1] =
                ((unsigned)(a & 31) << 16) | (unsigned)c;
        else {
            int o = atomicAdd(&ocur, 1);
            if (o < ovfcap) myovf[o] = ((unsigned)a << 16) | (unsigned)c;
        }
        int s2 = atomicAdd(&cur[gc], 1);
        if (s2 < CSLOT)
            bucket[((size_t)gc * SBLK + b) * CSLOT + s2] =
                ((unsigned)(c & 31) << 16) | (unsigned)a;
        else {
            int o = atomicAdd(&ocur, 1);
            if (o < ovfcap) myovf[o] = ((unsigned)c << 16) | (unsigned)a;
        }
    }
    __syncthreads();
    for (int g = t; g < G; g += STHR)
        cnt_t[(size_t)g * SBLK + b] = min(cur[g], CSLOT);
    if (t == 0) ovfcnt[b] = min(ocur, ovfcap);
}

// ---------------------------------------------------------------------------
// D: per group of 32 nodes — contiguous 16 KB cell sweep (masked by scnt) ->
// LDS bitmap with count-on-insert (all LDS atomics, no fences) -> dinv,
// then weighted colsum (x rows PREFETCHED before the insert loop to hide
// HBM latency under the LDS-atomic work) -> partial.
// LDS: bitmap unioned with the colsum-reduce scratch (bm dead by then).
// ---------------------------------------------------------------------------
union DedupLds {
    unsigned bm[32 * WPR];        // 48128 B (insert phase)
    float4   red[8][32];          // 4096 B  (colsum reduce; bm dead)
};

__global__ __launch_bounds__(256)
void k_dedup_colsum(const unsigned* __restrict__ bucket,
                    const int* __restrict__ cnt_t,
                    const int* __restrict__ ovfcnt,
                    const unsigned* __restrict__ ovf, int ovfcap,
                    const float4* __restrict__ x4,
                    float* __restrict__ dinv, float4* __restrict__ partial4,
                    int n, int G) {
    __shared__ DedupLds u;
    __shared__ int scnt[SBLK];
    __shared__ int socnt[SBLK];
    __shared__ int dcnt[32];
    __shared__ float dloc[32];
    int g = blockIdx.x, t = threadIdx.x;

    // prefetch this thread's 4 x-rows (issue-early; consumed after insert)
    int c4 = t & 31, ro = t >> 5;                 // ro 0..7
    float4 xv[4];
    #pragma unroll
    for (int k = 0; k < 4; ++k) {
        int node = g * 32 + ro + k * 8;
        xv[k] = (node < n) ? x4[(size_t)node * (F_IN / 4) + c4]
                           : make_float4(0.f, 0.f, 0.f, 0.f);
    }

    uint4* bm4 = (uint4*)u.bm;
    for (int i = t; i < (32 * WPR) / 4; i += 256)
        bm4[i] = make_uint4(0u, 0u, 0u, 0u);
    if (t < SBLK) { scnt[t] = cnt_t[(size_t)g * SBLK + t]; socnt[t] = ovfcnt[t]; }
    if (t < 32) dcnt[t] = 0;
    __syncthreads();

    // contiguous masked sweep: i -> (cell b = i>>5, slot s = i&31)
    const unsigned* gb = bucket + (size_t)g * SBLK * CSLOT;
    for (int i = t; i < SBLK * CSLOT; i += 256) {
        if ((i & 31) < scnt[i >> 5]) {
            unsigned w = gb[i];
            unsigned lrow = w >> 16, col = w & 0xFFFFu;
            unsigned bit = 1u << (col & 31);
            unsigned old = atomicOr(&u.bm[lrow * WPR + (col >> 5)], bit);
            if (!(old & bit)) atomicAdd(&dcnt[lrow], 1);
        }
    }
    // overflow lists (≈empty for random inputs; early-exit per block)
    for (int b = 0; b < SBLK; ++b) {
        int oc = socnt[b];
        if (oc == 0) continue;
        const unsigned* myovf = ovf + (size_t)b * ovfcap;
        for (int i = t; i < oc; i += 256) {
            unsigned w = myovf[i];
            unsigned node = w >> 16;
            if ((int)(node >> GBITS) == g) {
                unsigned lrow = node & 31, col = w & 0xFFFFu;
                unsigned bit = 1u << (col & 31);
                unsigned old = atomicOr(&u.bm[lrow * WPR + (col >> 5)], bit);
                if (!(old & bit)) atomicAdd(&dcnt[lrow], 1);
            }
        }
    }
    __syncthreads();

    if (t < 32) {
        float dv = 1.0f / sqrtf((float)dcnt[t]);   // deg==0 -> inf, matches ref
        dloc[t] = dv;
        int node = g * 32 + t;
        if (node < n) dinv[node] = dv;
    }
    __syncthreads();

    // colsum using prefetched xv; bm is dead -> reuse LDS as reduce scratch
    float4 acc = make_float4(0.f, 0.f, 0.f, 0.f);
    #pragma unroll
    for (int k = 0; k < 4; ++k) {
        float dv = dloc[ro + k * 8];               // inf*0 never occurs: xv=0 rows have dv used only if node<n... node>=n => xv=0 and dv*0=NaN? guard:
        int node = g * 32 + ro + k * 8;
        if (node < n) {
            acc.x += dv * xv[k].x; acc.y += dv * xv[k].y;
            acc.z += dv * xv[k].z; acc.w += dv * xv[k].w;
        }
    }
    __syncthreads();                               // ensure all bm reads done before overwrite
    u.red[ro][c4] = acc;
    __syncthreads();
    if (ro == 0) {
        float4 s = u.red[0][c4];
        #pragma unroll
        for (int k = 1; k < 8; ++k) {
            float4 v = u.red[k][c4];
            s.x += v.x; s.y += v.y; s.z += v.z; s.w += v.w;
        }
        partial4[(size_t)g * (F_IN / 4) + c4] = s;
    }
}

// ---------------------------------------------------------------------------
// R: single 1024-thread block. Reduce partials -> s[128], then
// agg[f] = sum_k s[k]*W[k,f] with 4-way k-split. (R8/R12/R14-verified.)
// ---------------------------------------------------------------------------
__global__ __launch_bounds__(1024)
void k_reduce_agg(const float4* __restrict__ partial4, int nparts,
                  const float* __restrict__ W, float* __restrict__ agg) {
    __shared__ float4 lds[32][32];
    __shared__ float s[F_IN];
    __shared__ float aggLds[4][F_OUT];
    int t = threadIdx.x;
    int c4 = t & 31;
    int g  = t >> 5;
    {
        float4 acc = make_float4(0.f, 0.f, 0.f, 0.f);
        for (int b = g; b < nparts; b += 32) {
            float4 v = partial4[(size_t)b * (F_IN / 4) + c4];
            acc.x += v.x; acc.y += v.y; acc.z += v.z; acc.w += v.w;
        }
        lds[g][c4] = acc;
    }
    __syncthreads();
    for (int st = 16; st > 0; st >>= 1) {
        if (g < st) {
            float4 o = lds[g + st][c4];
            float4 v = lds[g][c4];
            v.x += o.x; v.y += o.y; v.z += o.z; v.w += o.w;
            lds[g][c4] = v;
        }
        __syncthreads();
    }
    if (g == 0) {
        float4 v = lds[0][c4];
        s[c4 * 4 + 0] = v.x; s[c4 * 4 + 1] = v.y;
        s[c4 * 4 + 2] = v.z; s[c4 * 4 + 3] = v.w;
    }
    __syncthreads();
    {
        int f  = t & 255;
        int kg = t >> 8;
        float acc = 0.f;
        #pragma unroll 8
        for (int k = kg * 32; k < kg * 32 + 32; ++k)
            acc += s[k] * W[(size_t)k * F_OUT + f];
        aggLds[kg][f] = acc;
    }
    __syncthreads();
    if (t < F_OUT)
        agg[t] = aggLds[0][t] + aggLds[1][t] + aggLds[2][t] + aggLds[3][t];
}

// ---------------------------------------------------------------------------
// O: out[n,f] = dinv[n]*agg[f] + bias[f], float4-vectorized. (R8-verified.)
// ---------------------------------------------------------------------------
__global__ void k_outer(const float* __restrict__ dinv,
                        const float* __restrict__ agg,
                        const float* __restrict__ bias,
                        float4* __restrict__ out4, int n) {
    int i = blockIdx.x * blockDim.x + threadIdx.x;
    const int per_row = F_OUT / 4;
    int total = n * per_row;
    if (i >= total) return;
    int node = i >> 6;
    int f4   = i & 63;
    float d = dinv[node];
    float4 a  = ((const float4*)agg)[f4];
    float4 bb = ((const float4*)bias)[f4];
    float4 o;
    o.x = fmaf(d, a.x, bb.x);
    o.y = fmaf(d, a.y, bb.y);
    o.z = fmaf(d, a.z, bb.z);
    o.w = fmaf(d, a.w, bb.w);
    out4[i] = o;
}

// ===========================================================================
// Fallback (odd sizes / tiny workspace): round-4 global-bitmap path.
// ===========================================================================
__global__ __launch_bounds__(256)
void k_zero_simple(float4* __restrict__ p, size_t n4) {
    size_t i = (size_t)blockIdx.x * blockDim.x + threadIdx.x;
    size_t stride = (size_t)gridDim.x * blockDim.x;
    float4 z = make_float4(0.f, 0.f, 0.f, 0.f);
    for (; i < n4; i += stride) p[i] = z;
}
__global__ void k_set_bits_simple(const int* __restrict__ ei, int E,
                                  unsigned* __restrict__ bm, int r0, int r1,
                                  int row_words) {
    int e = blockIdx.x * blockDim.x + threadIdx.x;
    if (e >= E) return;
    int a = ei[e];
    int b = ei[E + e];
    if (a >= r0 && a < r1)
        atomicOr(&bm[(size_t)(a - r0) * row_words + (b >> 5)], 1u << (b & 31));
    if (b >= r0 && b < r1)
        atomicOr(&bm[(size_t)(b - r0) * row_words + (a >> 5)], 1u << (a & 31));
}
__global__ __launch_bounds__(256)
void k_degree_simple(const unsigned* __restrict__ bm, float* __restrict__ dinv,
                     int r0, int rows, int row_words) {
    int wave = threadIdx.x >> 6;
    int lane = threadIdx.x & 63;
    int row  = blockIdx.x * 4 + wave;
    if (row >= rows) return;
    const unsigned* p = bm + (size_t)row * row_words;
    int cnt = 0;
    for (int w = lane; w < row_words; w += 64)
        cnt += __popc(p[w]);
    #pragma unroll
    for (int off = 32; off > 0; off >>= 1)
        cnt += __shfl_down(cnt, off, 64);
    if (lane == 0)
        dinv[r0 + row] = 1.0f / sqrtf((float)cnt);
}
__global__ __launch_bounds__(256)
void k_colsum_simple(const float4* __restrict__ x4, const float* __restrict__ dinv,
                     float4* __restrict__ partial4, int n) {
    __shared__ float4 lds[8][32];
    int t = threadIdx.x;
    int c4 = t & 31;
    int ro = t >> 5;
    int rows_per = (n + (int)gridDim.x - 1) / (int)gridDim.x;
    int rbeg = blockIdx.x * rows_per;
    int rend = rbeg + rows_per; if (rend > n) rend = n;
    float4 acc = make_float4(0.f, 0.f, 0.f, 0.f);
    for (int r = rbeg + ro; r < rend; r += 8) {
        float dv = dinv[r];
        float4 v = x4[(size_t)r * (F_IN / 4) + c4];
        acc.x += dv * v.x; acc.y += dv * v.y;
        acc.z += dv * v.z; acc.w += dv * v.w;
    }
    lds[ro][c4] = acc;
    __syncthreads();
    if (ro == 0) {
        float4 s = lds[0][c4];
        #pragma unroll
        for (int g = 1; g < 8; ++g) {
            float4 v = lds[g][c4];
            s.x += v.x; s.y += v.y; s.z += v.z; s.w += v.w;
        }
        partial4[(size_t)blockIdx.x * (F_IN / 4) + c4] = s;
    }
}

// ---------------------------------------------------------------------------
static inline size_t align_up(size_t v, size_t a) { return (v + a - 1) & ~(a - 1); }

extern "C" void kernel_launch(void* const* d_in, const int* in_sizes, int n_in,
                              void* d_out, int out_size, void* d_ws, size_t ws_size,
                              hipStream_t stream) {
    const float* x    = (const float*)d_in[0];
    const int*   ei   = (const int*)  d_in[1];
    const float* W    = (const float*)d_in[2];
    const float* bias = (const float*)d_in[3];

    const int n = in_sizes[0] / F_IN;     // 12000
    const int E = in_sizes[1] / 2;        // 384000
    const int G = (n + 31) >> GBITS;      // 375
    const int C = (E + SBLK - 1) / SBLK;  // chunk size per scatter block
    const int ovfcap = (int)align_up((size_t)(2 * C), 64);   // whole chunk fits

    char* ws = (char*)d_ws;
    size_t off_b = 0;
    float* dinv = (float*)(ws + off_b); off_b = align_up(off_b + (size_t)n * 4, 256);
    float* agg  = (float*)(ws + off_b); off_b = align_up(off_b + (size_t)F_OUT * 4, 256);
    float4* partial4 = (float4*)(ws + off_b); off_b = align_up(off_b + (size_t)G * F_IN * 4, 256);
    int* cnt_t  = (int*)(ws + off_b); off_b = align_up(off_b + (size_t)G * SBLK * 4, 256);
    int* ovfcnt = (int*)(ws + off_b); off_b = align_up(off_b + (size_t)SBLK * 4, 256);
    unsigned* bucket = (unsigned*)(ws + off_b);
    off_b = align_up(off_b + (size_t)G * SBLK * CSLOT * 4, 256);
    unsigned* ovf = (unsigned*)(ws + off_b);
    size_t need = off_b + (size_t)SBLK * ovfcap * 4;

    bool fast = (G <= G_MAX) && (((n + 31) >> 5) <= WPR) && (n <= 65536) &&
                (need <= ws_size);

    if (fast) {
        k_scatter_cells<<<SBLK, STHR, 0, stream>>>(ei, E, G, cnt_t, ovfcnt,
                                                   bucket, ovf, ovfcap);
        k_dedup_colsum<<<G, 256, 0, stream>>>(bucket, cnt_t, ovfcnt, ovf, ovfcap,
                                              (const float4*)x, dinv, partial4,
                                              n, G);
        k_reduce_agg<<<1, 1024, 0, stream>>>(partial4, G, W, agg);
        int total4 = n * (F_OUT / 4);
        k_outer<<<(total4 + 255) / 256, 256, 0, stream>>>(dinv, agg, bias,
                                                          (float4*)d_out, n);
        return;
    }

    // ---- fallback: global-bitmap path ----
    const int row_words = (int)align_up((size_t)((n + 31) / 32), 64);
    const int NB = 512;
    size_t off_f = 0;
    float* dinv_f = (float*)(ws + off_f); off_f = align_up(off_f + (size_t)n * 4, 256);
    float* agg_f  = (float*)(ws + off_f); off_f = align_up(off_f + (size_t)F_OUT * 4, 256);
    float4* part_f = (float4*)(ws + off_f); off_f = align_up(off_f + (size_t)NB * F_IN * 4, 256);
    unsigned* bm = (unsigned*)(ws + off_f);
    size_t avail = (ws_size > off_f) ? (ws_size - off_f) : 0;
    long long fit = (long long)(avail / ((size_t)row_words * 4));
    int rows_per_chunk = (fit >= n) ? n : (fit > 0 ? (int)fit : 1);
    for (int r0 = 0; r0 < n; r0 += rows_per_chunk) {
        int rows = n - r0; if (rows > rows_per_chunk) rows = rows_per_chunk;
        size_t n4 = (size_t)rows * row_words / 4;
        int zgrid = (int)((n4 + 255) / 256); if (zgrid > 2048) zgrid = 2048;
        k_zero_simple<<<zgrid, 256, 0, stream>>>((float4*)bm, n4);
        k_set_bits_simple<<<(E + 255) / 256, 256, 0, stream>>>(ei, E, bm, r0, r0 + rows, row_words);
        k_degree_simple<<<(rows + 3) / 4, 256, 0, stream>>>(bm, dinv_f, r0, rows, row_words);
    }
    k_colsum_simple<<<NB, 256, 0, stream>>>((const float4*)x, dinv_f, part_f, n);
    k_reduce_agg<<<1, 1024, 0, stream>>>(part_f, NB, W, agg_f);
    int total4 = n * (F_OUT / 4);
    k_outer<<<(total4 + 255) / 256, 256, 0, stream>>>(dinv_f, agg_f, bias,
                                                      (float4*)d_out, n);
}

// Round 16
// 37.024 us; speedup vs baseline: 1.1445x; 1.1445x over previous
//
#include <hip/hip_runtime.h>
#include <math.h>

#define F_IN  128
#define F_OUT 256
#define GBITS 5            // 32 nodes per group
#define G_MAX 380          // max groups (G = ceil(n/32) = 375 for n=12000)
#define WPR   376          // padded words per LDS bitmap row (>= ceil(n/32))
#define SBLK  128          // scatter blocks
#define STHR  512          // scatter threads per block
#define CAP   4096         // arena slots per group (mean fill ~2048)
#define STAGE_CAP 8192     // LDS staging items per scatter block (32 KB)

// ---------------------------------------------------------------------------
// S: reservation scatter with BLOCK-LOCAL COUNTING SORT + coalesced copy-out.
// R14's reservation logic (one returning global atomic per non-empty group)
// is kept; the only change is HOW items reach the arena: instead of 768K
// scattered 4B writes (one line dirtied per item), items are placed
// group-sorted in LDS staging, then copied out linearly so each group's
// ~16-item run is 1-2 coalesced lines. Multiset written is exact; order /
// overflow split race-dependent; dedup ORs idempotently => deterministic.
// stage pack = node<<16 | other  (node < 65536 guaranteed by fast gate).
// arena pack = (node&31)<<16 | other ; ovf pack = node<<16 | other.
// ---------------------------------------------------------------------------
__global__ __launch_bounds__(STHR)
void k_scatter_sorted(const int* __restrict__ ei, int E, int G,
                      int* __restrict__ gcur,      // [G] zeroed before launch
                      int* __restrict__ ovfc,      // [1] zeroed before launch
                      unsigned* __restrict__ arena,// [G][CAP]
                      unsigned* __restrict__ ovf,  // [ovfcap]
                      int ovfcap) {
    __shared__ int hist[G_MAX];
    __shared__ int lofs[G_MAX];
    __shared__ int gbase[G_MAX];
    __shared__ int cur[G_MAX];
    __shared__ int sc[STHR];
    __shared__ int tot;
    __shared__ unsigned stage[STAGE_CAP];          // 32 KB
    int b = blockIdx.x, t = threadIdx.x;

    for (int g = t; g < G; g += STHR) hist[g] = 0;
    __syncthreads();

    int C = (E + (int)gridDim.x - 1) / (int)gridDim.x;
    int e0 = b * C, e1 = min(E, e0 + C);
    for (int e = e0 + t; e < e1; e += STHR) {
        int a = ei[e], c = ei[E + e];
        atomicAdd(&hist[a >> GBITS], 1);
        atomicAdd(&hist[c >> GBITS], 1);
    }
    __syncthreads();

    // 512-wide inclusive scan of hist (padded with zeros) -> sc
    sc[t] = (t < G) ? hist[t] : 0;
    __syncthreads();
    #pragma unroll
    for (int d = 1; d < STHR; d <<= 1) {
        int v = (t >= d) ? sc[t - d] : 0;
        __syncthreads();
        sc[t] += v;
        __syncthreads();
    }
    if (t == STHR - 1) tot = sc[t];
    if (t < G) {
        int h = hist[t];
        int lo = sc[t] - h;                        // exclusive prefix
        lofs[t] = lo;
        cur[t]  = lo;
        gbase[t] = h ? atomicAdd(&gcur[t], h) : 0; // reserve dense global range
    }
    __syncthreads();

    // place items group-sorted into LDS staging
    for (int e = e0 + t; e < e1; e += STHR) {
        int a = ei[e], c = ei[E + e];
        int s1 = atomicAdd(&cur[a >> GBITS], 1);
        stage[s1] = ((unsigned)a << 16) | (unsigned)c;
        int s2 = atomicAdd(&cur[c >> GBITS], 1);
        stage[s2] = ((unsigned)c << 16) | (unsigned)a;
    }
    __syncthreads();

    // coalesced copy-out: consecutive s -> consecutive arena slots per run
    int total = tot;
    for (int s = t; s < total; s += STHR) {
        unsigned w = stage[s];
        unsigned node = w >> 16;
        int g = (int)(node >> GBITS);
        int idx = gbase[g] + (s - lofs[g]);
        if (idx < CAP)
            arena[(size_t)g * CAP + idx] = ((node & 31u) << 16) | (w & 0xFFFFu);
        else {
            int o = atomicAdd(ovfc, 1);
            if (o < ovfcap) ovf[o] = w;
        }
    }
}

// ---------------------------------------------------------------------------
// D: per group of 32 nodes — dense arena read -> LDS bitmap with
// COUNT-ON-INSERT (all LDS atomics, no fences) -> dinv, then weighted
// colsum -> partial. (Byte-identical to R14's verified kernel.)
// ---------------------------------------------------------------------------
__global__ __launch_bounds__(256)
void k_dedup_colsum(const unsigned* __restrict__ arena,
                    const int* __restrict__ gcur,
                    const int* __restrict__ ovfc,
                    const unsigned* __restrict__ ovf, int ovfcap,
                    const float4* __restrict__ x4,
                    float* __restrict__ dinv, float4* __restrict__ partial4,
                    int n, int G) {
    __shared__ __align__(16) unsigned bm[32 * WPR];   // 48128 B
    __shared__ int dcnt[32];
    __shared__ float dloc[32];
    __shared__ float4 red[8][32];
    int g = blockIdx.x, t = threadIdx.x;

    uint4* bm4 = (uint4*)bm;
    for (int i = t; i < (32 * WPR) / 4; i += 256)
        bm4[i] = make_uint4(0u, 0u, 0u, 0u);
    if (t < 32) dcnt[t] = 0;
    __syncthreads();

    int cnt = gcur[g]; if (cnt > CAP) cnt = CAP;
    const unsigned* ga = arena + (size_t)g * CAP;
    for (int i = t; i < cnt; i += 256) {
        unsigned w = ga[i];
        unsigned lrow = w >> 16, col = w & 0xFFFFu;
        unsigned bit = 1u << (col & 31);
        unsigned old = atomicOr(&bm[lrow * WPR + (col >> 5)], bit);
        if (!(old & bit)) atomicAdd(&dcnt[lrow], 1);
    }
    int oc = *ovfc; if (oc > ovfcap) oc = ovfcap;
    if (oc > 0) {
        for (int i = t; i < oc; i += 256) {
            unsigned w = ovf[i];
            unsigned node = w >> 16;
            if ((int)(node >> GBITS) == g) {
                unsigned lrow = node & 31, col = w & 0xFFFFu;
                unsigned bit = 1u << (col & 31);
                unsigned old = atomicOr(&bm[lrow * WPR + (col >> 5)], bit);
                if (!(old & bit)) atomicAdd(&dcnt[lrow], 1);
            }
        }
    }
    __syncthreads();

    if (t < 32) {
        float dv = 1.0f / sqrtf((float)dcnt[t]);   // deg==0 -> inf, matches ref
        dloc[t] = dv;
        int node = g * 32 + t;
        if (node < n) dinv[node] = dv;
    }
    __syncthreads();

    int c4 = t & 31, ro = t >> 5;         // ro 0..7
    float4 acc = make_float4(0.f, 0.f, 0.f, 0.f);
    for (int lr = ro; lr < 32; lr += 8) {
        int node = g * 32 + lr;
        if (node >= n) break;
        float dv = dloc[lr];
        float4 v = x4[(size_t)node * (F_IN / 4) + c4];
        acc.x += dv * v.x; acc.y += dv * v.y;
        acc.z += dv * v.z; acc.w += dv * v.w;
    }
    red[ro][c4] = acc;
    __syncthreads();
    if (ro == 0) {
        float4 s = red[0][c4];
        #pragma unroll
        for (int k = 1; k < 8; ++k) {
            float4 v = red[k][c4];
            s.x += v.x; s.y += v.y; s.z += v.z; s.w += v.w;
        }
        partial4[(size_t)g * (F_IN / 4) + c4] = s;
    }
}

// ---------------------------------------------------------------------------
// R: single 1024-thread block. Reduce partials -> s[128], then
// agg[f] = sum_k s[k]*W[k,f] with 4-way k-split. (R8/R12/R14-verified.)
// ---------------------------------------------------------------------------
__global__ __launch_bounds__(1024)
void k_reduce_agg(const float4* __restrict__ partial4, int nparts,
                  const float* __restrict__ W, float* __restrict__ agg) {
    __shared__ float4 lds[32][32];
    __shared__ float s[F_IN];
    __shared__ float aggLds[4][F_OUT];
    int t = threadIdx.x;
    int c4 = t & 31;
    int g  = t >> 5;
    {
        float4 acc = make_float4(0.f, 0.f, 0.f, 0.f);
        for (int b = g; b < nparts; b += 32) {
            float4 v = partial4[(size_t)b * (F_IN / 4) + c4];
            acc.x += v.x; acc.y += v.y; acc.z += v.z; acc.w += v.w;
        }
        lds[g][c4] = acc;
    }
    __syncthreads();
    for (int st = 16; st > 0; st >>= 1) {
        if (g < st) {
            float4 o = lds[g + st][c4];
            float4 v = lds[g][c4];
            v.x += o.x; v.y += o.y; v.z += o.z; v.w += o.w;
            lds[g][c4] = v;
        }
        __syncthreads();
    }
    if (g == 0) {
        float4 v = lds[0][c4];
        s[c4 * 4 + 0] = v.x; s[c4 * 4 + 1] = v.y;
        s[c4 * 4 + 2] = v.z; s[c4 * 4 + 3] = v.w;
    }
    __syncthreads();
    {
        int f  = t & 255;
        int kg = t >> 8;
        float acc = 0.f;
        #pragma unroll 8
        for (int k = kg * 32; k < kg * 32 + 32; ++k)
            acc += s[k] * W[(size_t)k * F_OUT + f];
        aggLds[kg][f] = acc;
    }
    __syncthreads();
    if (t < F_OUT)
        agg[t] = aggLds[0][t] + aggLds[1][t] + aggLds[2][t] + aggLds[3][t];
}

// ---------------------------------------------------------------------------
// O: out[n,f] = dinv[n]*agg[f] + bias[f], float4-vectorized. (R8-verified.)
// ---------------------------------------------------------------------------
__global__ void k_outer(const float* __restrict__ dinv,
                        const float* __restrict__ agg,
                        const float* __restrict__ bias,
                        float4* __restrict__ out4, int n) {
    int i = blockIdx.x * blockDim.x + threadIdx.x;
    const int per_row = F_OUT / 4;
    int total = n * per_row;
    if (i >= total) return;
    int node = i >> 6;
    int f4   = i & 63;
    float d = dinv[node];
    float4 a  = ((const float4*)agg)[f4];
    float4 bb = ((const float4*)bias)[f4];
    float4 o;
    o.x = fmaf(d, a.x, bb.x);
    o.y = fmaf(d, a.y, bb.y);
    o.z = fmaf(d, a.z, bb.z);
    o.w = fmaf(d, a.w, bb.w);
    out4[i] = o;
}

// ===========================================================================
// Fallback (odd sizes / tiny workspace): round-4 global-bitmap path.
// ===========================================================================
__global__ __launch_bounds__(256)
void k_zero_simple(float4* __restrict__ p, size_t n4) {
    size_t i = (size_t)blockIdx.x * blockDim.x + threadIdx.x;
    size_t stride = (size_t)gridDim.x * blockDim.x;
    float4 z = make_float4(0.f, 0.f, 0.f, 0.f);
    for (; i < n4; i += stride) p[i] = z;
}
__global__ void k_set_bits_simple(const int* __restrict__ ei, int E,
                                  unsigned* __restrict__ bm, int r0, int r1,
                                  int row_words) {
    int e = blockIdx.x * blockDim.x + threadIdx.x;
    if (e >= E) return;
    int a = ei[e];
    int b = ei[E + e];
    if (a >= r0 && a < r1)
        atomicOr(&bm[(size_t)(a - r0) * row_words + (b >> 5)], 1u << (b & 31));
    if (b >= r0 && b < r1)
        atomicOr(&bm[(size_t)(b - r0) * row_words + (a >> 5)], 1u << (a & 31));
}
__global__ __launch_bounds__(256)
void k_degree_simple(const unsigned* __restrict__ bm, float* __restrict__ dinv,
                     int r0, int rows, int row_words) {
    int wave = threadIdx.x >> 6;
    int lane = threadIdx.x & 63;
    int row  = blockIdx.x * 4 + wave;
    if (row >= rows) return;
    const unsigned* p = bm + (size_t)row * row_words;
    int cnt = 0;
    for (int w = lane; w < row_words; w += 64)
        cnt += __popc(p[w]);
    #pragma unroll
    for (int off = 32; off > 0; off >>= 1)
        cnt += __shfl_down(cnt, off, 64);
    if (lane == 0)
        dinv[r0 + row] = 1.0f / sqrtf((float)cnt);
}
__global__ __launch_bounds__(256)
void k_colsum_simple(const float4* __restrict__ x4, const float* __restrict__ dinv,
                     float4* __restrict__ partial4, int n) {
    __shared__ float4 lds[8][32];
    int t = threadIdx.x;
    int c4 = t & 31;
    int ro = t >> 5;
    int rows_per = (n + (int)gridDim.x - 1) / (int)gridDim.x;
    int rbeg = blockIdx.x * rows_per;
    int rend = rbeg + rows_per; if (rend > n) rend = n;
    float4 acc = make_float4(0.f, 0.f, 0.f, 0.f);
    for (int r = rbeg + ro; r < rend; r += 8) {
        float dv = dinv[r];
        float4 v = x4[(size_t)r * (F_IN / 4) + c4];
        acc.x += dv * v.x; acc.y += dv * v.y;
        acc.z += dv * v.z; acc.w += dv * v.w;
    }
    lds[ro][c4] = acc;
    __syncthreads();
    if (ro == 0) {
        float4 s = lds[0][c4];
        #pragma unroll
        for (int g = 1; g < 8; ++g) {
            float4 v = lds[g][c4];
            s.x += v.x; s.y += v.y; s.z += v.z; s.w += v.w;
        }
        partial4[(size_t)blockIdx.x * (F_IN / 4) + c4] = s;
    }
}

// ---------------------------------------------------------------------------
static inline size_t align_up(size_t v, size_t a) { return (v + a - 1) & ~(a - 1); }

extern "C" void kernel_launch(void* const* d_in, const int* in_sizes, int n_in,
                              void* d_out, int out_size, void* d_ws, size_t ws_size,
                              hipStream_t stream) {
    const float* x    = (const float*)d_in[0];
    const int*   ei   = (const int*)  d_in[1];
    const float* W    = (const float*)d_in[2];
    const float* bias = (const float*)d_in[3];

    const int n = in_sizes[0] / F_IN;     // 12000
    const int E = in_sizes[1] / 2;        // 384000
    const int G = (n + 31) >> GBITS;      // 375
    const int ovfcap = 2 * E;             // can never drop an item
    const int C = (E + SBLK - 1) / SBLK;  // edges per scatter block

    char* ws = (char*)d_ws;
    size_t off_b = 0;
    float* dinv = (float*)(ws + off_b); off_b = align_up(off_b + (size_t)n * 4, 256);
    float* agg  = (float*)(ws + off_b); off_b = align_up(off_b + (size_t)F_OUT * 4, 256);
    float4* partial4 = (float4*)(ws + off_b); off_b = align_up(off_b + (size_t)G * F_IN * 4, 256);
    int* gcur = (int*)(ws + off_b);        // [G] counters + [1] ovfc, contiguous
    int* ovfc = gcur + G;
    off_b = align_up(off_b + (size_t)(G + 1) * 4, 256);
    unsigned* arena = (unsigned*)(ws + off_b);
    off_b = align_up(off_b + (size_t)G * CAP * 4, 256);
    unsigned* ovf = (unsigned*)(ws + off_b);
    size_t need = off_b + (size_t)ovfcap * 4;

    bool fast = (G <= G_MAX) && (((n + 31) >> 5) <= WPR) && (n <= 65536) &&
                (2 * C <= STAGE_CAP) && (need <= ws_size);

    if (fast) {
        (void)hipMemsetAsync(gcur, 0, (size_t)(G + 1) * 4, stream);
        k_scatter_sorted<<<SBLK, STHR, 0, stream>>>(ei, E, G, gcur, ovfc,
                                                    arena, ovf, ovfcap);
        k_dedup_colsum<<<G, 256, 0, stream>>>(arena, gcur, ovfc, ovf, ovfcap,
                                              (const float4*)x, dinv, partial4,
                                              n, G);
        k_reduce_agg<<<1, 1024, 0, stream>>>(partial4, G, W, agg);
        int total4 = n * (F_OUT / 4);
        k_outer<<<(total4 + 255) / 256, 256, 0, stream>>>(dinv, agg, bias,
                                                          (float4*)d_out, n);
        return;
    }

    // ---- fallback: global-bitmap path ----
    const int row_words = (int)align_up((size_t)((n + 31) / 32), 64);
    const int NB = 512;
    size_t off_f = 0;
    float* dinv_f = (float*)(ws + off_f); off_f = align_up(off_f + (size_t)n * 4, 256);
    float* agg_f  = (float*)(ws + off_f); off_f = align_up(off_f + (size_t)F_OUT * 4, 256);
    float4* part_f = (float4*)(ws + off_f); off_f = align_up(off_f + (size_t)NB * F_IN * 4, 256);
    unsigned* bm = (unsigned*)(ws + off_f);
    size_t avail = (ws_size > off_f) ? (ws_size - off_f) : 0;
    long long fit = (long long)(avail / ((size_t)row_words * 4));
    int rows_per_chunk = (fit >= n) ? n : (fit > 0 ? (int)fit : 1);
    for (int r0 = 0; r0 < n; r0 += rows_per_chunk) {
        int rows = n - r0; if (rows > rows_per_chunk) rows = rows_per_chunk;
        size_t n4 = (size_t)rows * row_words / 4;
        int zgrid = (int)((n4 + 255) / 256); if (zgrid > 2048) zgrid = 2048;
        k_zero_simple<<<zgrid, 256, 0, stream>>>((float4*)bm, n4);
        k_set_bits_simple<<<(E + 255) / 256, 256, 0, stream>>>(ei, E, bm, r0, r0 + rows, row_words);
        k_degree_simple<<<(rows + 3) / 4, 256, 0, stream>>>(bm, dinv_f, r0, rows, row_words);
    }
    k_colsum_simple<<<NB, 256, 0, stream>>>((const float4*)x, dinv_f, part_f, n);
    k_reduce_agg<<<1, 1024, 0, stream>>>(part_f, NB, W, agg_f);
    int total4 = n * (F_OUT / 4);
    k_outer<<<(total4 + 255) / 256, 256, 0, stream>>>(dinv_f, agg_f, bias,
                                                      (float4*)d_out, n);
}

// Round 17
// 33.616 us; speedup vs baseline: 1.2605x; 1.1014x over previous
//
#include <hip/hip_runtime.h>
#include <math.h>

#define F_IN  128
#define F_OUT 256
#define GBITS 5            // 32 nodes per group
#define G_MAX 380          // max groups (G = ceil(n/32) = 375 for n=12000)
#define WPR   376          // padded words per LDS bitmap row (>= ceil(n/32))
#define SBLK  128          // scatter blocks (dedup assumes 2 threads/run -> 256)
#define STHR  512          // scatter threads per block
#define STAGE_CAP 8192     // LDS staging items per scatter block (32 KB)

// ---------------------------------------------------------------------------
// S: block-region scatter. Fully deterministic addressing; NO global atomics,
// NO pre-zeroed memory, NO overflow (region capacity = 2*chunk, exact bound).
// Per block: LDS histogram -> 512-wide scan -> counting-sort into LDS stage
// -> contiguous coalesced copy to blockout[b][0..tot) -> publish run bounds
// lofs_t[g][b] (row G = tot). Run content order is race-permuted within a
// run; the per-run SET is exact and consumed via idempotent OR downstream.
// pack = node<<16 | other  (node < 65536 guaranteed by the fast gate).
// ---------------------------------------------------------------------------
__global__ __launch_bounds__(STHR)
void k_scatter_blockout(const int* __restrict__ ei, int E, int G,
                        int* __restrict__ lofs_t,        // [(G+1)][SBLK]
                        unsigned* __restrict__ blockout, // [SBLK][rcap]
                        int rcap) {
    __shared__ int hist[G_MAX];
    __shared__ int cur[G_MAX];
    __shared__ int sc[STHR];
    __shared__ unsigned stage[STAGE_CAP];          // 32 KB
    int b = blockIdx.x, t = threadIdx.x;

    for (int g = t; g < G; g += STHR) hist[g] = 0;
    __syncthreads();

    int C = (E + (int)gridDim.x - 1) / (int)gridDim.x;
    int e0 = b * C, e1 = min(E, e0 + C);
    for (int e = e0 + t; e < e1; e += STHR) {
        int a = ei[e], c = ei[E + e];
        atomicAdd(&hist[a >> GBITS], 1);
        atomicAdd(&hist[c >> GBITS], 1);
    }
    __syncthreads();

    // 512-wide inclusive scan of hist (zero-padded) -> sc; sc[511] = tot
    sc[t] = (t < G) ? hist[t] : 0;
    __syncthreads();
    #pragma unroll
    for (int d = 1; d < STHR; d <<= 1) {
        int v = (t >= d) ? sc[t - d] : 0;
        __syncthreads();
        sc[t] += v;
        __syncthreads();
    }
    if (t < G) {
        int lo = sc[t] - hist[t];                  // exclusive prefix
        cur[t] = lo;
        lofs_t[(size_t)t * SBLK + b] = lo;
    }
    if (t == 0) lofs_t[(size_t)G * SBLK + b] = sc[STHR - 1];
    __syncthreads();

    // counting-sort placement into LDS staging
    for (int e = e0 + t; e < e1; e += STHR) {
        int a = ei[e], c = ei[E + e];
        int s1 = atomicAdd(&cur[a >> GBITS], 1);
        stage[s1] = ((unsigned)a << 16) | (unsigned)c;
        int s2 = atomicAdd(&cur[c >> GBITS], 1);
        stage[s2] = ((unsigned)c << 16) | (unsigned)a;
    }
    __syncthreads();

    // contiguous, fully-coalesced copy-out to this block's region
    int tot = sc[STHR - 1];
    unsigned* myout = blockout + (size_t)b * rcap;
    for (int s = t; s < tot; s += STHR)
        myout[s] = stage[s];
}

// ---------------------------------------------------------------------------
// D: per group of 32 nodes. Fetch = 128 short runs (2 threads per run) located
// by lofs_t[g][b]..lofs_t[g+1][b] -> LDS bitmap with COUNT-ON-INSERT (all LDS
// atomics, no fences) -> dinv, then weighted colsum -> partial.
// Consumer phases byte-identical to R14/R16's verified kernel.
// ---------------------------------------------------------------------------
union DedupLds {
    unsigned bm[32 * WPR];        // 48128 B (insert phase)
    float4   red[8][32];          // 4 KB   (colsum reduce; bm dead)
};

__global__ __launch_bounds__(256)
void k_dedup_colsum(const unsigned* __restrict__ blockout,
                    const int* __restrict__ lofs_t, int rcap,
                    const float4* __restrict__ x4,
                    float* __restrict__ dinv, float4* __restrict__ partial4,
                    int n, int G) {
    __shared__ DedupLds u;
    __shared__ int dcnt[32];
    __shared__ float dloc[32];
    int g = blockIdx.x, t = threadIdx.x;

    uint4* bm4 = (uint4*)u.bm;
    for (int i = t; i < (32 * WPR) / 4; i += 256)
        bm4[i] = make_uint4(0u, 0u, 0u, 0u);
    if (t < 32) dcnt[t] = 0;
    __syncthreads();

    // 2 threads per scatter-block run: b = t>>1, parity-strided items
    {
        int b = t >> 1, half = t & 1;
        int lo = lofs_t[(size_t)g       * SBLK + b];
        int hi = lofs_t[(size_t)(g + 1) * SBLK + b];
        const unsigned* mo = blockout + (size_t)b * rcap;
        for (int i = lo + half; i < hi; i += 2) {
            unsigned w = mo[i];
            unsigned lrow = (w >> 16) & 31u, col = w & 0xFFFFu;
            unsigned bit = 1u << (col & 31);
            unsigned old = atomicOr(&u.bm[lrow * WPR + (col >> 5)], bit);
            if (!(old & bit)) atomicAdd(&dcnt[lrow], 1);
        }
    }
    __syncthreads();

    if (t < 32) {
        float dv = 1.0f / sqrtf((float)dcnt[t]);   // deg==0 -> inf, matches ref
        dloc[t] = dv;
        int node = g * 32 + t;
        if (node < n) dinv[node] = dv;
    }
    __syncthreads();

    int c4 = t & 31, ro = t >> 5;         // ro 0..7
    float4 acc = make_float4(0.f, 0.f, 0.f, 0.f);
    for (int lr = ro; lr < 32; lr += 8) {
        int node = g * 32 + lr;
        if (node >= n) break;
        float dv = dloc[lr];
        float4 v = x4[(size_t)node * (F_IN / 4) + c4];
        acc.x += dv * v.x; acc.y += dv * v.y;
        acc.z += dv * v.z; acc.w += dv * v.w;
    }
    __syncthreads();                      // bm reads done; reuse LDS as scratch
    u.red[ro][c4] = acc;
    __syncthreads();
    if (ro == 0) {
        float4 s = u.red[0][c4];
        #pragma unroll
        for (int k = 1; k < 8; ++k) {
            float4 v = u.red[k][c4];
            s.x += v.x; s.y += v.y; s.z += v.z; s.w += v.w;
        }
        partial4[(size_t)g * (F_IN / 4) + c4] = s;
    }
}

// ---------------------------------------------------------------------------
// R: single 1024-thread block. Reduce partials -> s[128], then
// agg[f] = sum_k s[k]*W[k,f] with 4-way k-split. (R8/R12/R14-verified.)
// ---------------------------------------------------------------------------
__global__ __launch_bounds__(1024)
void k_reduce_agg(const float4* __restrict__ partial4, int nparts,
                  const float* __restrict__ W, float* __restrict__ agg) {
    __shared__ float4 lds[32][32];
    __shared__ float s[F_IN];
    __shared__ float aggLds[4][F_OUT];
    int t = threadIdx.x;
    int c4 = t & 31;
    int g  = t >> 5;
    {
        float4 acc = make_float4(0.f, 0.f, 0.f, 0.f);
        for (int b = g; b < nparts; b += 32) {
            float4 v = partial4[(size_t)b * (F_IN / 4) + c4];
            acc.x += v.x; acc.y += v.y; acc.z += v.z; acc.w += v.w;
        }
        lds[g][c4] = acc;
    }
    __syncthreads();
    for (int st = 16; st > 0; st >>= 1) {
        if (g < st) {
            float4 o = lds[g + st][c4];
            float4 v = lds[g][c4];
            v.x += o.x; v.y += o.y; v.z += o.z; v.w += o.w;
            lds[g][c4] = v;
        }
        __syncthreads();
    }
    if (g == 0) {
        float4 v = lds[0][c4];
        s[c4 * 4 + 0] = v.x; s[c4 * 4 + 1] = v.y;
        s[c4 * 4 + 2] = v.z; s[c4 * 4 + 3] = v.w;
    }
    __syncthreads();
    {
        int f  = t & 255;
        int kg = t >> 8;
        float acc = 0.f;
        #pragma unroll 8
        for (int k = kg * 32; k < kg * 32 + 32; ++k)
            acc += s[k] * W[(size_t)k * F_OUT + f];
        aggLds[kg][f] = acc;
    }
    __syncthreads();
    if (t < F_OUT)
        agg[t] = aggLds[0][t] + aggLds[1][t] + aggLds[2][t] + aggLds[3][t];
}

// ---------------------------------------------------------------------------
// O: out[n,f] = dinv[n]*agg[f] + bias[f], float4-vectorized. (R8-verified.)
// ---------------------------------------------------------------------------
__global__ void k_outer(const float* __restrict__ dinv,
                        const float* __restrict__ agg,
                        const float* __restrict__ bias,
                        float4* __restrict__ out4, int n) {
    int i = blockIdx.x * blockDim.x + threadIdx.x;
    const int per_row = F_OUT / 4;
    int total = n * per_row;
    if (i >= total) return;
    int node = i >> 6;
    int f4   = i & 63;
    float d = dinv[node];
    float4 a  = ((const float4*)agg)[f4];
    float4 bb = ((const float4*)bias)[f4];
    float4 o;
    o.x = fmaf(d, a.x, bb.x);
    o.y = fmaf(d, a.y, bb.y);
    o.z = fmaf(d, a.z, bb.z);
    o.w = fmaf(d, a.w, bb.w);
    out4[i] = o;
}

// ===========================================================================
// Fallback (odd sizes / tiny workspace): round-4 global-bitmap path.
// ===========================================================================
__global__ __launch_bounds__(256)
void k_zero_simple(float4* __restrict__ p, size_t n4) {
    size_t i = (size_t)blockIdx.x * blockDim.x + threadIdx.x;
    size_t stride = (size_t)gridDim.x * blockDim.x;
    float4 z = make_float4(0.f, 0.f, 0.f, 0.f);
    for (; i < n4; i += stride) p[i] = z;
}
__global__ void k_set_bits_simple(const int* __restrict__ ei, int E,
                                  unsigned* __restrict__ bm, int r0, int r1,
                                  int row_words) {
    int e = blockIdx.x * blockDim.x + threadIdx.x;
    if (e >= E) return;
    int a = ei[e];
    int b = ei[E + e];
    if (a >= r0 && a < r1)
        atomicOr(&bm[(size_t)(a - r0) * row_words + (b >> 5)], 1u << (b & 31));
    if (b >= r0 && b < r1)
        atomicOr(&bm[(size_t)(b - r0) * row_words + (a >> 5)], 1u << (a & 31));
}
__global__ __launch_bounds__(256)
void k_degree_simple(const unsigned* __restrict__ bm, float* __restrict__ dinv,
                     int r0, int rows, int row_words) {
    int wave = threadIdx.x >> 6;
    int lane = threadIdx.x & 63;
    int row  = blockIdx.x * 4 + wave;
    if (row >= rows) return;
    const unsigned* p = bm + (size_t)row * row_words;
    int cnt = 0;
    for (int w = lane; w < row_words; w += 64)
        cnt += __popc(p[w]);
    #pragma unroll
    for (int off = 32; off > 0; off >>= 1)
        cnt += __shfl_down(cnt, off, 64);
    if (lane == 0)
        dinv[r0 + row] = 1.0f / sqrtf((float)cnt);
}
__global__ __launch_bounds__(256)
void k_colsum_simple(const float4* __restrict__ x4, const float* __restrict__ dinv,
                     float4* __restrict__ partial4, int n) {
    __shared__ float4 lds[8][32];
    int t = threadIdx.x;
    int c4 = t & 31;
    int ro = t >> 5;
    int rows_per = (n + (int)gridDim.x - 1) / (int)gridDim.x;
    int rbeg = blockIdx.x * rows_per;
    int rend = rbeg + rows_per; if (rend > n) rend = n;
    float4 acc = make_float4(0.f, 0.f, 0.f, 0.f);
    for (int r = rbeg + ro; r < rend; r += 8) {
        float dv = dinv[r];
        float4 v = x4[(size_t)r * (F_IN / 4) + c4];
        acc.x += dv * v.x; acc.y += dv * v.y;
        acc.z += dv * v.z; acc.w += dv * v.w;
    }
    lds[ro][c4] = acc;
    __syncthreads();
    if (ro == 0) {
        float4 s = lds[0][c4];
        #pragma unroll
        for (int g = 1; g < 8; ++g) {
            float4 v = lds[g][c4];
            s.x += v.x; s.y += v.y; s.z += v.z; s.w += v.w;
        }
        partial4[(size_t)blockIdx.x * (F_IN / 4) + c4] = s;
    }
}

// ---------------------------------------------------------------------------
static inline size_t align_up(size_t v, size_t a) { return (v + a - 1) & ~(a - 1); }

extern "C" void kernel_launch(void* const* d_in, const int* in_sizes, int n_in,
                              void* d_out, int out_size, void* d_ws, size_t ws_size,
                              hipStream_t stream) {
    const float* x    = (const float*)d_in[0];
    const int*   ei   = (const int*)  d_in[1];
    const float* W    = (const float*)d_in[2];
    const float* bias = (const float*)d_in[3];

    const int n = in_sizes[0] / F_IN;     // 12000
    const int E = in_sizes[1] / 2;        // 384000
    const int G = (n + 31) >> GBITS;      // 375
    const int C = (E + SBLK - 1) / SBLK;  // edges per scatter block (3000)
    const int rcap = (int)align_up((size_t)(2 * C), 64);  // region words (exact bound)

    char* ws = (char*)d_ws;
    size_t off_b = 0;
    float* dinv = (float*)(ws + off_b); off_b = align_up(off_b + (size_t)n * 4, 256);
    float* agg  = (float*)(ws + off_b); off_b = align_up(off_b + (size_t)F_OUT * 4, 256);
    float4* partial4 = (float4*)(ws + off_b); off_b = align_up(off_b + (size_t)G * F_IN * 4, 256);
    int* lofs_t = (int*)(ws + off_b); off_b = align_up(off_b + (size_t)(G + 1) * SBLK * 4, 256);
    unsigned* blockout = (unsigned*)(ws + off_b);
    size_t need = off_b + (size_t)SBLK * rcap * 4;

    bool fast = (G <= G_MAX) && (((n + 31) >> 5) <= WPR) && (n <= 65536) &&
                (2 * C <= STAGE_CAP) && (need <= ws_size);

    if (fast) {
        k_scatter_blockout<<<SBLK, STHR, 0, stream>>>(ei, E, G, lofs_t,
                                                      blockout, rcap);
        k_dedup_colsum<<<G, 256, 0, stream>>>(blockout, lofs_t, rcap,
                                              (const float4*)x, dinv, partial4,
                                              n, G);
        k_reduce_agg<<<1, 1024, 0, stream>>>(partial4, G, W, agg);
        int total4 = n * (F_OUT / 4);
        k_outer<<<(total4 + 255) / 256, 256, 0, stream>>>(dinv, agg, bias,
                                                          (float4*)d_out, n);
        return;
    }

    // ---- fallback: global-bitmap path ----
    const int row_words = (int)align_up((size_t)((n + 31) / 32), 64);
    const int NB = 512;
    size_t off_f = 0;
    float* dinv_f = (float*)(ws + off_f); off_f = align_up(off_f + (size_t)n * 4, 256);
    float* agg_f  = (float*)(ws + off_f); off_f = align_up(off_f + (size_t)F_OUT * 4, 256);
    float4* part_f = (float4*)(ws + off_f); off_f = align_up(off_f + (size_t)NB * F_IN * 4, 256);
    unsigned* bm = (unsigned*)(ws + off_f);
    size_t avail = (ws_size > off_f) ? (ws_size - off_f) : 0;
    long long fit = (long long)(avail / ((size_t)row_words * 4));
    int rows_per_chunk = (fit >= n) ? n : (fit > 0 ? (int)fit : 1);
    for (int r0 = 0; r0 < n; r0 += rows_per_chunk) {
        int rows = n - r0; if (rows > rows_per_chunk) rows = rows_per_chunk;
        size_t n4 = (size_t)rows * row_words / 4;
        int zgrid = (int)((n4 + 255) / 256); if (zgrid > 2048) zgrid = 2048;
        k_zero_simple<<<zgrid, 256, 0, stream>>>((float4*)bm, n4);
        k_set_bits_simple<<<(E + 255) / 256, 256, 0, stream>>>(ei, E, bm, r0, r0 + rows, row_words);
        k_degree_simple<<<(rows + 3) / 4, 256, 0, stream>>>(bm, dinv_f, r0, rows, row_words);
    }
    k_colsum_simple<<<NB, 256, 0, stream>>>((const float4*)x, dinv_f, part_f, n);
    k_reduce_agg<<<1, 1024, 0, stream>>>(part_f, NB, W, agg_f);
    int total4 = n * (F_OUT / 4);
    k_outer<<<(total4 + 255) / 256, 256, 0, stream>>>(dinv_f, agg_f, bias,
                                                      (float4*)d_out, n);
}